// Round 12
// baseline (269.819 us; speedup 1.0000x reference)
//
#include <hip/hip_runtime.h>

constexpr int HID = 32;
constexpr int OUTC = 16;
constexpr int BIN = 256;      // dst-nodes per partition bin
constexpr int BSH = 8;        // log2(BIN)
constexpr int MAXNB = 1024;   // max bins (N <= 256K)
constexpr int PTILE = 2048;   // edges per k_part block (8 per thread)

typedef int iv4 __attribute__((ext_vector_type(4)));

static __device__ __forceinline__ float4 ld4(const float* p) { return *(const float4*)p; }

// zero bcnt (4KB): tiny kernel instead of blit fill (R10 lesson: the blit paid
// ~43us/replay of cross-XCD invalidation).
__global__ void k_zero(int* __restrict__ bcnt) {
    bcnt[threadIdx.x] = 0;
}

// One-pass radix partition. Entry packed to 4B: (src<<8)|(dst&255); bin = dst>>8.
// Requires N < 2^24 (here N=100K).
__global__ void k_part(const int* __restrict__ src, const int* __restrict__ dst,
                       int* __restrict__ bcnt, int* __restrict__ elist,
                       int E, int nb, int capb) {
    __shared__ int hist[MAXNB];
    __shared__ int base[MAXNB];
    const int t = threadIdx.x;
    for (int i = t; i < nb; i += blockDim.x) hist[i] = 0;
    __syncthreads();
    const int E4 = E >> 2;
    int d[8], s[8], r[8];
    bool val[2];
#pragma unroll
    for (int q = 0; q < 2; ++q) {
        const int v = blockIdx.x * (PTILE / 4) + q * 256 + t;
        val[q] = (v < E4);
        if (val[q]) {
            iv4 d4 = __builtin_nontemporal_load(((const iv4*)dst) + v);
            iv4 s4 = __builtin_nontemporal_load(((const iv4*)src) + v);
            d[q*4+0] = d4.x; d[q*4+1] = d4.y; d[q*4+2] = d4.z; d[q*4+3] = d4.w;
            s[q*4+0] = s4.x; s[q*4+1] = s4.y; s[q*4+2] = s4.z; s[q*4+3] = s4.w;
#pragma unroll
            for (int k = q*4; k < q*4+4; ++k) r[k] = atomicAdd(&hist[d[k] >> BSH], 1);
        }
    }
    __syncthreads();
    for (int i = t; i < nb; i += blockDim.x) {
        int h = hist[i];
        base[i] = h ? atomicAdd(&bcnt[i], h) : 0;
    }
    __syncthreads();
#pragma unroll
    for (int q = 0; q < 2; ++q) {
        if (val[q]) {
#pragma unroll
            for (int k = q*4; k < q*4+4; ++k) {
                int bin = d[k] >> BSH;
                int pos = base[bin] + r[k];
                if (pos < capb) elist[(size_t)bin * capb + pos] = (s[k] << BSH) | (d[k] & (BIN-1));
            }
        }
    }
    if (blockIdx.x == 0 && t < (E & 3)) {
        int j = (E4 << 2) + t;
        int dd = dst[j], ss = src[j];
        int bin = dd >> BSH;
        int pos = atomicAdd(&bcnt[bin], 1);
        if (pos < capb) elist[(size_t)bin * capb + pos] = (ss << BSH) | (dd & (BIN-1));
    }
}

// Per-bin degree count (LDS) -> dinv = rsqrt(deg+1), y = x*dinv.
__global__ void k_degbin(const int* __restrict__ elist, const int* __restrict__ bcnt,
                         const float* __restrict__ x, float* __restrict__ dinv,
                         float* __restrict__ y, int capb, int N) {
    __shared__ int cnt[BIN];
    const int b = blockIdx.x;
    const int tid = threadIdx.x;
    if (tid < BIN) cnt[tid] = 0;
    __syncthreads();
    const int ecnt = min(bcnt[b], capb);
    const int* lst = elist + (size_t)b * capb;
    for (int i0 = tid * 4; i0 + 3 < ecnt; i0 += blockDim.x * 4) {
        iv4 e = *(const iv4*)(lst + i0);
        atomicAdd(&cnt[e.x & (BIN-1)], 1);
        atomicAdd(&cnt[e.y & (BIN-1)], 1);
        atomicAdd(&cnt[e.z & (BIN-1)], 1);
        atomicAdd(&cnt[e.w & (BIN-1)], 1);
    }
    if (tid < (ecnt & 3)) atomicAdd(&cnt[lst[(ecnt & ~3) + tid] & (BIN-1)], 1);
    __syncthreads();
    const int node = (b << BSH) + tid;
    if (tid < BIN && node < N) {
        float di = 1.0f / sqrtf((float)(cnt[tid] + 1));   // +1 = self-loop
        dinv[node] = di;
        float4 xv = ld4(x + (size_t)node * 4);
        float4 yv; yv.x = xv.x * di; yv.y = xv.y * di; yv.z = xv.z * di; yv.w = xv.w * di;
        *(float4*)(y + (size_t)node * 4) = yv;
    }
}

// Layer 1 (+W1+relu+W2 fused), block per bin, LDS accumulator BIN x 4 (4KB).
// Edge phase: stream bin's elist (coalesced iv4), gather y[s] (16B, L2-resident
// 1.6MB), 4 LDS float atomics into acc[dst_local]. Epilogue per node:
// sv=(acc+y[n])*dinv -> r=relu(sv@W1+b1) -> z=(r@W2)*dinv.
__global__ void __launch_bounds__(512) k_l1(
        const int* __restrict__ elist, const int* __restrict__ bcnt,
        const float* __restrict__ dinv, const float* __restrict__ y,
        const float* __restrict__ W1, const float* __restrict__ b1,
        const float* __restrict__ W2, float* __restrict__ z, int capb, int N) {
    __shared__ float acc[BIN * 4];           // 4KB
    __shared__ float sW1[4 * HID];
    __shared__ float sb1[HID];
    __shared__ float sW2[HID * OUTC];
    const int tid = threadIdx.x;
    for (int i = tid; i < BIN * 4; i += blockDim.x) acc[i] = 0.f;
    if (tid < 4 * HID) sW1[tid] = W1[tid];
    if (tid < HID) sb1[tid] = b1[tid];
    if (tid < HID * OUTC) sW2[tid] = W2[tid];  // 512 threads cover 512 elems
    __syncthreads();

    const int b = blockIdx.x;
    const int ecnt = min(bcnt[b], capb);
    const int* lst = elist + (size_t)b * capb;
    for (int i0 = tid * 4; i0 + 3 < ecnt; i0 += blockDim.x * 4) {
        iv4 e = *(const iv4*)(lst + i0);
        int l0 = e.x & (BIN-1), s0 = (unsigned)e.x >> BSH;
        int l1 = e.y & (BIN-1), s1 = (unsigned)e.y >> BSH;
        int l2 = e.z & (BIN-1), s2 = (unsigned)e.z >> BSH;
        int l3 = e.w & (BIN-1), s3 = (unsigned)e.w >> BSH;
        float4 y0 = ld4(y + (size_t)s0 * 4);
        float4 y1 = ld4(y + (size_t)s1 * 4);
        float4 y2 = ld4(y + (size_t)s2 * 4);
        float4 y3 = ld4(y + (size_t)s3 * 4);
        atomicAdd(&acc[l0*4+0], y0.x); atomicAdd(&acc[l0*4+1], y0.y);
        atomicAdd(&acc[l0*4+2], y0.z); atomicAdd(&acc[l0*4+3], y0.w);
        atomicAdd(&acc[l1*4+0], y1.x); atomicAdd(&acc[l1*4+1], y1.y);
        atomicAdd(&acc[l1*4+2], y1.z); atomicAdd(&acc[l1*4+3], y1.w);
        atomicAdd(&acc[l2*4+0], y2.x); atomicAdd(&acc[l2*4+1], y2.y);
        atomicAdd(&acc[l2*4+2], y2.z); atomicAdd(&acc[l2*4+3], y2.w);
        atomicAdd(&acc[l3*4+0], y3.x); atomicAdd(&acc[l3*4+1], y3.y);
        atomicAdd(&acc[l3*4+2], y3.z); atomicAdd(&acc[l3*4+3], y3.w);
    }
    if (tid < (ecnt & 3)) {
        int e = lst[(ecnt & ~3) + tid];
        int l = e & (BIN-1);
        float4 yv = ld4(y + (size_t)((unsigned)e >> BSH) * 4);
        atomicAdd(&acc[l*4+0], yv.x); atomicAdd(&acc[l*4+1], yv.y);
        atomicAdd(&acc[l*4+2], yv.z); atomicAdd(&acc[l*4+3], yv.w);
    }
    __syncthreads();

    // epilogue: 512 threads = 256 nodes x 2 halves; half h -> out channels h*8..h*8+7
    const int nl = tid >> 1, h = tid & 1;
    const int node = (b << BSH) + nl;
    if (node < N) {
        const float di = dinv[node];
        float4 yn = ld4(y + (size_t)node * 4);
        float4 sv;
        sv.x = (acc[nl*4+0] + yn.x) * di;
        sv.y = (acc[nl*4+1] + yn.y) * di;
        sv.z = (acc[nl*4+2] + yn.z) * di;
        sv.w = (acc[nl*4+3] + yn.w) * di;
        float r[HID];
#pragma unroll
        for (int c = 0; c < HID; ++c)
            r[c] = fmaxf(sv.x * sW1[c] + sv.y * sW1[HID + c] +
                         sv.z * sW1[2*HID + c] + sv.w * sW1[3*HID + c] + sb1[c], 0.f);
        float o[8] = {};
#pragma unroll
        for (int k = 0; k < HID; ++k) {
            const float rk = r[k];
#pragma unroll
            for (int c = 0; c < 8; ++c) o[c] += rk * sW2[k * OUTC + h * 8 + c];
        }
        float* op = z + (size_t)node * OUTC + h * 8;
#pragma unroll
        for (int c = 0; c < 8; c += 4) {
            float4 v; v.x = o[c]*di; v.y = o[c+1]*di; v.z = o[c+2]*di; v.w = o[c+3]*di;
            *(float4*)(op + c) = v;
        }
    }
}

// Layer 2, block per bin, LDS accumulator BIN x 16 (16KB).
// Edge phase: 2 edges/thread/iter, 8 z-row quarter gathers in flight,
// 16 LDS atomics per edge. Epilogue: out = (acc + z[n])*dinv + b2.
__global__ void __launch_bounds__(512) k_l2(
        const int* __restrict__ elist, const int* __restrict__ bcnt,
        const float* __restrict__ dinv, const float* __restrict__ z,
        const float* __restrict__ b2, float* __restrict__ out, int capb, int N) {
    __shared__ float acc[BIN * OUTC];        // 16KB
    __shared__ float sb[OUTC];
    const int tid = threadIdx.x;
    for (int i = tid; i < BIN * OUTC; i += blockDim.x) acc[i] = 0.f;
    if (tid < OUTC) sb[tid] = b2[tid];
    __syncthreads();

    const int b = blockIdx.x;
    const int ecnt = min(bcnt[b], capb);
    const int* lst = elist + (size_t)b * capb;
    for (int i0 = tid * 2; i0 + 1 < ecnt; i0 += blockDim.x * 2) {
        int e0 = lst[i0], e1 = lst[i0 + 1];
        int l0 = (e0 & (BIN-1)) << 4, s0 = (unsigned)e0 >> BSH;
        int l1 = (e1 & (BIN-1)) << 4, s1 = (unsigned)e1 >> BSH;
        const float* z0 = z + (size_t)s0 * OUTC;
        const float* z1 = z + (size_t)s1 * OUTC;
        float4 a0 = ld4(z0), a1 = ld4(z0 + 4), a2 = ld4(z0 + 8), a3 = ld4(z0 + 12);
        float4 c0 = ld4(z1), c1 = ld4(z1 + 4), c2 = ld4(z1 + 8), c3 = ld4(z1 + 12);
        atomicAdd(&acc[l0+0],  a0.x); atomicAdd(&acc[l0+1],  a0.y);
        atomicAdd(&acc[l0+2],  a0.z); atomicAdd(&acc[l0+3],  a0.w);
        atomicAdd(&acc[l0+4],  a1.x); atomicAdd(&acc[l0+5],  a1.y);
        atomicAdd(&acc[l0+6],  a1.z); atomicAdd(&acc[l0+7],  a1.w);
        atomicAdd(&acc[l0+8],  a2.x); atomicAdd(&acc[l0+9],  a2.y);
        atomicAdd(&acc[l0+10], a2.z); atomicAdd(&acc[l0+11], a2.w);
        atomicAdd(&acc[l0+12], a3.x); atomicAdd(&acc[l0+13], a3.y);
        atomicAdd(&acc[l0+14], a3.z); atomicAdd(&acc[l0+15], a3.w);
        atomicAdd(&acc[l1+0],  c0.x); atomicAdd(&acc[l1+1],  c0.y);
        atomicAdd(&acc[l1+2],  c0.z); atomicAdd(&acc[l1+3],  c0.w);
        atomicAdd(&acc[l1+4],  c1.x); atomicAdd(&acc[l1+5],  c1.y);
        atomicAdd(&acc[l1+6],  c1.z); atomicAdd(&acc[l1+7],  c1.w);
        atomicAdd(&acc[l1+8],  c2.x); atomicAdd(&acc[l1+9],  c2.y);
        atomicAdd(&acc[l1+10], c2.z); atomicAdd(&acc[l1+11], c2.w);
        atomicAdd(&acc[l1+12], c3.x); atomicAdd(&acc[l1+13], c3.y);
        atomicAdd(&acc[l1+14], c3.z); atomicAdd(&acc[l1+15], c3.w);
    }
    if ((ecnt & 1) && tid == 0) {
        int e = lst[ecnt - 1];
        int l = (e & (BIN-1)) << 4;
        const float* zp = z + (size_t)((unsigned)e >> BSH) * OUTC;
        for (int c = 0; c < OUTC; ++c) atomicAdd(&acc[l + c], zp[c]);
    }
    __syncthreads();

    // epilogue: 512 threads = 256 nodes x 2 halves of the 16-ch row
    const int nl = tid >> 1, h = (tid & 1) * 8;
    const int node = (b << BSH) + nl;
    if (node < N) {
        const float di = dinv[node];
        const float* zp = z + (size_t)node * OUTC + h;
        float* op = out + (size_t)node * OUTC + h;
#pragma unroll
        for (int c = 0; c < 8; c += 4) {
            float4 av = *(const float4*)(acc + nl * OUTC + h + c);
            float4 zv = ld4(zp + c);
            float4 o;
            o.x = (av.x + zv.x) * di + sb[h + c + 0];
            o.y = (av.y + zv.y) * di + sb[h + c + 1];
            o.z = (av.z + zv.z) * di + sb[h + c + 2];
            o.w = (av.w + zv.w) * di + sb[h + c + 3];
            *(float4*)(op + c) = o;
        }
    }
}

extern "C" void kernel_launch(void* const* d_in, const int* in_sizes, int n_in,
                              void* d_out, int out_size, void* d_ws, size_t ws_size,
                              hipStream_t stream) {
    const float* x  = (const float*)d_in[0];
    const int*   ei = (const int*)d_in[1];
    const float* W1 = (const float*)d_in[2];
    const float* b1 = (const float*)d_in[3];
    const float* W2 = (const float*)d_in[4];
    const float* b2 = (const float*)d_in[5];

    const int N = in_sizes[0] / 4;   // in_c = 4
    const int E = in_sizes[1] / 2;   // edge_index is (2, E)
    const int* src = ei;
    const int* dst = ei + E;

    const int nb = (N + BIN - 1) >> BSH;   // 391 bins at N=100K

    auto align = [](size_t v) { return (v + 255) & ~(size_t)255; };
    // per-bin capacity (multiple of 4): mean E/nb ~4092, sd ~64; +1024 = 16 sigma
    int capb = (E / nb + 1024 + 3) & ~3;
    {
        size_t fixed = align((size_t)MAXNB * 4) + align((size_t)N * 4) +
                       align((size_t)N * 4 * 4) + align((size_t)N * OUTC * 4);
        while (capb > E / nb + 128 && fixed + align((size_t)nb * (size_t)capb * 4) > ws_size)
            capb -= 256;
    }

    char* ws = (char*)d_ws;
    size_t off = 0;
    int*   bcnt  = (int*)(ws + off);   off += align((size_t)MAXNB * 4);
    float* dinv  = (float*)(ws + off); off += align((size_t)N * 4);
    float* y     = (float*)(ws + off); off += align((size_t)N * 4 * 4);
    float* z     = (float*)(ws + off); off += align((size_t)N * OUTC * 4);
    int*   elist = (int*)(ws + off);   off += align((size_t)nb * (size_t)capb * 4);
    (void)n_in;

    k_zero<<<1, MAXNB, 0, stream>>>(bcnt);
    k_part<<<(E + PTILE - 1) / PTILE, 256, 0, stream>>>(src, dst, bcnt, elist, E, nb, capb);
    k_degbin<<<nb, 512, 0, stream>>>(elist, bcnt, x, dinv, y, capb, N);
    k_l1<<<nb, 512, 0, stream>>>(elist, bcnt, dinv, y, W1, b1, W2, z, capb, N);
    k_l2<<<nb, 512, 0, stream>>>(elist, bcnt, dinv, z, b2, (float*)d_out, capb, N);
    (void)out_size;
}

// Round 13
// 93.664 us; speedup vs baseline: 2.8807x; 2.8807x over previous
//
#include <hip/hip_runtime.h>

constexpr int HID = 32;
constexpr int OUTC = 16;
constexpr int BIN = 256;      // dst-nodes per partition bin
constexpr int BSH = 8;        // log2(BIN)
constexpr int MAXNB = 1024;   // max bins (N <= 256K)
constexpr int PTILE = 2048;   // edges per k_part block (8 per thread)

typedef int iv4 __attribute__((ext_vector_type(4)));

static __device__ __forceinline__ float4 ld4(const float* p) { return *(const float4*)p; }

// zero bcnt (4KB): tiny kernel instead of blit fill (R10 lesson: blit fill
// paid ~43us/replay of cross-XCD invalidation on dirty lines).
__global__ void k_zero(int* __restrict__ bcnt) {
    bcnt[threadIdx.x] = 0;
}

// One-pass radix partition. Entry packed to 4B: (src<<8)|(dst&255); bin = dst>>8.
// Requires N < 2^24 (here N=100K).
__global__ void k_part(const int* __restrict__ src, const int* __restrict__ dst,
                       int* __restrict__ bcnt, int* __restrict__ elist,
                       int E, int nb, int capb) {
    __shared__ int hist[MAXNB];
    __shared__ int base[MAXNB];
    const int t = threadIdx.x;
    for (int i = t; i < nb; i += blockDim.x) hist[i] = 0;
    __syncthreads();
    const int E4 = E >> 2;
    int d[8], s[8], r[8];
    bool val[2];
#pragma unroll
    for (int q = 0; q < 2; ++q) {
        const int v = blockIdx.x * (PTILE / 4) + q * 256 + t;
        val[q] = (v < E4);
        if (val[q]) {
            iv4 d4 = __builtin_nontemporal_load(((const iv4*)dst) + v);
            iv4 s4 = __builtin_nontemporal_load(((const iv4*)src) + v);
            d[q*4+0] = d4.x; d[q*4+1] = d4.y; d[q*4+2] = d4.z; d[q*4+3] = d4.w;
            s[q*4+0] = s4.x; s[q*4+1] = s4.y; s[q*4+2] = s4.z; s[q*4+3] = s4.w;
#pragma unroll
            for (int k = q*4; k < q*4+4; ++k) r[k] = atomicAdd(&hist[d[k] >> BSH], 1);
        }
    }
    __syncthreads();
    for (int i = t; i < nb; i += blockDim.x) {
        int h = hist[i];
        base[i] = h ? atomicAdd(&bcnt[i], h) : 0;
    }
    __syncthreads();
#pragma unroll
    for (int q = 0; q < 2; ++q) {
        if (val[q]) {
#pragma unroll
            for (int k = q*4; k < q*4+4; ++k) {
                int bin = d[k] >> BSH;
                int pos = base[bin] + r[k];
                if (pos < capb) elist[(size_t)bin * capb + pos] = (s[k] << BSH) | (d[k] & (BIN-1));
            }
        }
    }
    if (blockIdx.x == 0 && t < (E & 3)) {
        int j = (E4 << 2) + t;
        int dd = dst[j], ss = src[j];
        int bin = dd >> BSH;
        int pos = atomicAdd(&bcnt[bin], 1);
        if (pos < capb) elist[(size_t)bin * capb + pos] = (ss << BSH) | (dd & (BIN-1));
    }
}

// One block per bin; degree counting via LDS atomics. Exclusive bin ownership:
// eidx slice (64KB) stores stay in one L2. Epilogue: cursor=deg (write-once),
// dinv = rsqrt(deg+1), y = x*dinv.
__global__ void k_fill3(const int* __restrict__ elist, const int* __restrict__ bcnt,
                        int* __restrict__ cursor, int* __restrict__ eidx,
                        const float* __restrict__ x, float* __restrict__ dinv,
                        float* __restrict__ y, int capb, int CAP, int N) {
    __shared__ int cnt[BIN];
    const int b = blockIdx.x;
    const int bin0 = b << BSH;
    const int tid = threadIdx.x;
    if (tid < BIN) cnt[tid] = 0;
    __syncthreads();
    const int ecnt = min(bcnt[b], capb);
    const int* lst = elist + (size_t)b * capb;
    for (int i0 = tid * 4; i0 + 3 < ecnt; i0 += blockDim.x * 4) {
        iv4 e = *(const iv4*)(lst + i0);
        int l0 = e.x & (BIN-1), s0 = (unsigned)e.x >> BSH;
        int l1 = e.y & (BIN-1), s1 = (unsigned)e.y >> BSH;
        int l2 = e.z & (BIN-1), s2 = (unsigned)e.z >> BSH;
        int l3 = e.w & (BIN-1), s3 = (unsigned)e.w >> BSH;
        int p0 = atomicAdd(&cnt[l0], 1);
        int p1 = atomicAdd(&cnt[l1], 1);
        int p2 = atomicAdd(&cnt[l2], 1);
        int p3 = atomicAdd(&cnt[l3], 1);
        if (p0 < CAP) eidx[(size_t)(bin0 + l0) * CAP + p0] = s0;
        if (p1 < CAP) eidx[(size_t)(bin0 + l1) * CAP + p1] = s1;
        if (p2 < CAP) eidx[(size_t)(bin0 + l2) * CAP + p2] = s2;
        if (p3 < CAP) eidx[(size_t)(bin0 + l3) * CAP + p3] = s3;
    }
    const int tb = ecnt & ~3;
    if (tid < (ecnt & 3)) {
        int e = lst[tb + tid];
        int l = e & (BIN-1);
        int pos = atomicAdd(&cnt[l], 1);
        if (pos < CAP) eidx[(size_t)(bin0 + l) * CAP + pos] = (unsigned)e >> BSH;
    }
    __syncthreads();
    const int node = bin0 + tid;            // threads 0..255 handle the bin's nodes
    if (tid < BIN && node < N) {
        int deg = cnt[tid];
        cursor[node] = deg;                                  // write-once (no pre-zero)
        float di = 1.0f / sqrtf((float)(deg + 1));           // +1 = self-loop
        dinv[node] = di;
        float4 xv = ld4(x + (size_t)node * 4);
        float4 yv; yv.x = xv.x * di; yv.y = xv.y * di; yv.z = xv.z * di; yv.w = xv.w * di;
        *(float4*)(y + (size_t)node * 4) = yv;
    }
}

// Layer 1 + gemm2 fused, 4 LANES PER NODE (R13: R11's 1-thread/node was
// TLP-starved at ~1.5 waves/SIMD; 4 lanes/node quadruples resident waves).
// Lane g handles quads g, g+4, ... of the bucket (one iv4 idx load + 4
// y-gathers, ILP=4); shfl_xor 4-lane reduce; epilogue W2 matvec split 4-way
// (lane g computes output channels g*4..g*4+3).
__global__ void __launch_bounds__(256) k_layer1(
        const int* __restrict__ eidx, const int* __restrict__ degv,
        const float* __restrict__ dinv, const float* __restrict__ y,
        const float* __restrict__ W1, const float* __restrict__ b1,
        const float* __restrict__ W2, float* __restrict__ z, int N, int CAP) {
    __shared__ float sW1[4 * HID];
    __shared__ float sb1[HID];
    __shared__ float sW2[HID * OUTC];
    const int tid = threadIdx.x;
    if (tid < 4 * HID) sW1[tid] = W1[tid];
    if (tid < HID) sb1[tid] = b1[tid];
    for (int i = tid; i < HID * OUTC; i += blockDim.x) sW2[i] = W2[i];
    __syncthreads();
    const int g = tid & 3;
    const int n = blockIdx.x * (blockDim.x >> 2) + (tid >> 2);
    if (n >= N) return;
    const int deg = min(degv[n], CAP);
    const int* bucket = eidx + (size_t)n * CAP;
    float4 a = {0,0,0,0};
    for (int base = g * 4; base + 3 < deg; base += 16) {
        iv4 q = *(const iv4*)(bucket + base);
        float4 y0 = ld4(y + (size_t)q.x * 4);
        float4 y1 = ld4(y + (size_t)q.y * 4);
        float4 y2 = ld4(y + (size_t)q.z * 4);
        float4 y3 = ld4(y + (size_t)q.w * 4);
        a.x += (y0.x + y1.x) + (y2.x + y3.x);
        a.y += (y0.y + y1.y) + (y2.y + y3.y);
        a.z += (y0.z + y1.z) + (y2.z + y3.z);
        a.w += (y0.w + y1.w) + (y2.w + y3.w);
    }
    const int tb = deg & ~3;
    if (g < (deg & 3)) {
        float4 yv = ld4(y + (size_t)bucket[tb + g] * 4);
        a.x += yv.x; a.y += yv.y; a.z += yv.z; a.w += yv.w;
    }
    // 4-lane reduce (each lane ends with the full sum)
    a.x += __shfl_xor(a.x, 1); a.y += __shfl_xor(a.y, 1);
    a.z += __shfl_xor(a.z, 1); a.w += __shfl_xor(a.w, 1);
    a.x += __shfl_xor(a.x, 2); a.y += __shfl_xor(a.y, 2);
    a.z += __shfl_xor(a.z, 2); a.w += __shfl_xor(a.w, 2);

    const float di = dinv[n];
    float4 yn = ld4(y + (size_t)n * 4);
    float4 sv;
    sv.x = (a.x + yn.x) * di;
    sv.y = (a.y + yn.y) * di;
    sv.z = (a.z + yn.z) * di;
    sv.w = (a.w + yn.w) * di;
    float r[HID];
#pragma unroll
    for (int c = 0; c < HID; ++c)
        r[c] = fmaxf(sv.x * sW1[c] + sv.y * sW1[HID + c] +
                     sv.z * sW1[2*HID + c] + sv.w * sW1[3*HID + c] + sb1[c], 0.f);
    float o[4] = {};
#pragma unroll
    for (int k = 0; k < HID; ++k) {
        const float rk = r[k];
#pragma unroll
        for (int c = 0; c < 4; ++c) o[c] += rk * sW2[k * OUTC + g * 4 + c];
    }
    float4 v;
    v.x = o[0] * di; v.y = o[1] * di; v.z = o[2] * di; v.w = o[3] * di;
    *(float4*)(z + (size_t)n * OUTC + g * 4) = v;
}

// Layer 2: 4 LANES PER NODE, lane l owns channels l*4..l*4+3 (unchanged, R11).
__global__ void k_agg2(const int* __restrict__ eidx, const int* __restrict__ degv,
                       const float* __restrict__ dinv, const float* __restrict__ z,
                       const float* __restrict__ b2, float* __restrict__ out,
                       int N, int CAP) {
    __shared__ float sb[OUTC];
    if (threadIdx.x < OUTC) sb[threadIdx.x] = b2[threadIdx.x];
    __syncthreads();
    const int tid = threadIdx.x;
    const int l4 = (tid & 3) * 4;
    const int n = blockIdx.x * (blockDim.x >> 2) + (tid >> 2);
    if (n >= N) return;
    const int deg = min(degv[n], CAP);
    const int* bucket = eidx + (size_t)n * CAP;
    float4 acc = {0,0,0,0}, acc2 = {0,0,0,0};
    int i = 0;
    for (; i + 7 < deg; i += 8) {
        iv4 q0 = *(const iv4*)(bucket + i);
        iv4 q1 = *(const iv4*)(bucket + i + 4);
        float4 r0 = ld4(z + (size_t)q0.x * OUTC + l4);
        float4 r1 = ld4(z + (size_t)q0.y * OUTC + l4);
        float4 r2 = ld4(z + (size_t)q0.z * OUTC + l4);
        float4 r3 = ld4(z + (size_t)q0.w * OUTC + l4);
        float4 r4 = ld4(z + (size_t)q1.x * OUTC + l4);
        float4 r5 = ld4(z + (size_t)q1.y * OUTC + l4);
        float4 r6 = ld4(z + (size_t)q1.z * OUTC + l4);
        float4 r7 = ld4(z + (size_t)q1.w * OUTC + l4);
        acc.x += r0.x + r1.x; acc.y += r0.y + r1.y; acc.z += r0.z + r1.z; acc.w += r0.w + r1.w;
        acc2.x += r2.x + r3.x; acc2.y += r2.y + r3.y; acc2.z += r2.z + r3.z; acc2.w += r2.w + r3.w;
        acc.x += r4.x + r5.x; acc.y += r4.y + r5.y; acc.z += r4.z + r5.z; acc.w += r4.w + r5.w;
        acc2.x += r6.x + r7.x; acc2.y += r6.y + r7.y; acc2.z += r6.z + r7.z; acc2.w += r6.w + r7.w;
    }
    for (; i + 3 < deg; i += 4) {
        iv4 q0 = *(const iv4*)(bucket + i);
        float4 r0 = ld4(z + (size_t)q0.x * OUTC + l4);
        float4 r1 = ld4(z + (size_t)q0.y * OUTC + l4);
        float4 r2 = ld4(z + (size_t)q0.z * OUTC + l4);
        float4 r3 = ld4(z + (size_t)q0.w * OUTC + l4);
        acc.x += r0.x + r1.x; acc.y += r0.y + r1.y; acc.z += r0.z + r1.z; acc.w += r0.w + r1.w;
        acc2.x += r2.x + r3.x; acc2.y += r2.y + r3.y; acc2.z += r2.z + r3.z; acc2.w += r2.w + r3.w;
    }
    for (; i < deg; ++i) {
        float4 r = ld4(z + (size_t)bucket[i] * OUTC + l4);
        acc.x += r.x; acc.y += r.y; acc.z += r.z; acc.w += r.w;
    }
    const float di = dinv[n];
    float4 zn = ld4(z + (size_t)n * OUTC + l4);
    float4 o;
    o.x = (acc.x + acc2.x + zn.x) * di + sb[l4 + 0];
    o.y = (acc.y + acc2.y + zn.y) * di + sb[l4 + 1];
    o.z = (acc.z + acc2.z + zn.z) * di + sb[l4 + 2];
    o.w = (acc.w + acc2.w + zn.w) * di + sb[l4 + 3];
    *(float4*)(out + (size_t)n * OUTC + l4) = o;
}

extern "C" void kernel_launch(void* const* d_in, const int* in_sizes, int n_in,
                              void* d_out, int out_size, void* d_ws, size_t ws_size,
                              hipStream_t stream) {
    const float* x  = (const float*)d_in[0];
    const int*   ei = (const int*)d_in[1];
    const float* W1 = (const float*)d_in[2];
    const float* b1 = (const float*)d_in[3];
    const float* W2 = (const float*)d_in[4];
    const float* b2 = (const float*)d_in[5];

    const int N = in_sizes[0] / 4;   // in_c = 4
    const int E = in_sizes[1] / 2;   // edge_index is (2, E)
    const int* src = ei;
    const int* dst = ei + E;

    const int nb = (N + BIN - 1) >> BSH;   // 391 bins at N=100K

    auto align = [](size_t v) { return (v + 255) & ~(size_t)255; };
    int capb = (E / nb + 1024 + 3) & ~3;   // mean E/nb ~4092, sd ~64
    int CAP = 64;                          // Poisson(16): P(deg>64) ~ 1e-13/node
    auto total = [&](int cap, int cb) {
        return align((size_t)N * 4) + align((size_t)MAXNB * 4) + align((size_t)N * 4) +
               align((size_t)N * 4 * 4) + align((size_t)N * OUTC * 4) +
               align((size_t)N * cap * 4) + align((size_t)nb * (size_t)cb * 4);
    };
    while (capb > E / nb + 128 && total(CAP, capb) > ws_size) capb -= 256;
    while (CAP > 40 && total(CAP, capb) > ws_size) CAP -= 8;

    char* ws = (char*)d_ws;
    size_t off = 0;
    int*   cursor = (int*)(ws + off);   off += align((size_t)N * 4);
    int*   bcnt   = (int*)(ws + off);   off += align((size_t)MAXNB * 4);
    float* dinv   = (float*)(ws + off); off += align((size_t)N * 4);
    float* y      = (float*)(ws + off); off += align((size_t)N * 4 * 4);
    float* z      = (float*)(ws + off); off += align((size_t)N * OUTC * 4);
    int*   eidx   = (int*)(ws + off);   off += align((size_t)N * CAP * 4);
    int*   elist  = (int*)(ws + off);   off += align((size_t)nb * (size_t)capb * 4);
    (void)n_in;

    k_zero<<<1, MAXNB, 0, stream>>>(bcnt);
    k_part<<<(E + PTILE - 1) / PTILE, 256, 0, stream>>>(src, dst, bcnt, elist, E, nb, capb);
    k_fill3<<<nb, 512, 0, stream>>>(elist, bcnt, cursor, eidx, x, dinv, y, capb, CAP, N);
    k_layer1<<<(N + 63) / 64, 256, 0, stream>>>(eidx, cursor, dinv, y, W1, b1, W2, z, N, CAP);
    k_agg2<<<(N + 63) / 64, 256, 0, stream>>>(eidx, cursor, dinv, z, b2, (float*)d_out, N, CAP);
    (void)out_size;
}

// Round 14
// 92.757 us; speedup vs baseline: 2.9089x; 1.0098x over previous
//
#include <hip/hip_runtime.h>

constexpr int HID = 32;
constexpr int OUTC = 16;
constexpr int BIN = 256;      // dst-nodes per partition bin
constexpr int BSH = 8;        // log2(BIN)
constexpr int MAXNB = 1024;   // max bins (N <= 256K)
constexpr int PTILE = 2048;   // edges per k_part block (8 per thread)

typedef int iv4 __attribute__((ext_vector_type(4)));

static __device__ __forceinline__ float4 ld4(const float* p) { return *(const float4*)p; }

// zero bcnt (4KB): tiny kernel instead of blit fill (R10 lesson: blit fill
// paid ~43us/replay of cross-XCD invalidation on dirty lines).
__global__ void k_zero(int* __restrict__ bcnt) {
    bcnt[threadIdx.x] = 0;
}

// One-pass radix partition. Entry packed to 4B: (src<<8)|(dst&255); bin = dst>>8.
// Requires N < 2^24 (here N=100K).
__global__ void k_part(const int* __restrict__ src, const int* __restrict__ dst,
                       int* __restrict__ bcnt, int* __restrict__ elist,
                       int E, int nb, int capb) {
    __shared__ int hist[MAXNB];
    __shared__ int base[MAXNB];
    const int t = threadIdx.x;
    for (int i = t; i < nb; i += blockDim.x) hist[i] = 0;
    __syncthreads();
    const int E4 = E >> 2;
    int d[8], s[8], r[8];
    bool val[2];
#pragma unroll
    for (int q = 0; q < 2; ++q) {
        const int v = blockIdx.x * (PTILE / 4) + q * 256 + t;
        val[q] = (v < E4);
        if (val[q]) {
            iv4 d4 = __builtin_nontemporal_load(((const iv4*)dst) + v);
            iv4 s4 = __builtin_nontemporal_load(((const iv4*)src) + v);
            d[q*4+0] = d4.x; d[q*4+1] = d4.y; d[q*4+2] = d4.z; d[q*4+3] = d4.w;
            s[q*4+0] = s4.x; s[q*4+1] = s4.y; s[q*4+2] = s4.z; s[q*4+3] = s4.w;
#pragma unroll
            for (int k = q*4; k < q*4+4; ++k) r[k] = atomicAdd(&hist[d[k] >> BSH], 1);
        }
    }
    __syncthreads();
    for (int i = t; i < nb; i += blockDim.x) {
        int h = hist[i];
        base[i] = h ? atomicAdd(&bcnt[i], h) : 0;
    }
    __syncthreads();
#pragma unroll
    for (int q = 0; q < 2; ++q) {
        if (val[q]) {
#pragma unroll
            for (int k = q*4; k < q*4+4; ++k) {
                int bin = d[k] >> BSH;
                int pos = base[bin] + r[k];
                if (pos < capb) elist[(size_t)bin * capb + pos] = (s[k] << BSH) | (d[k] & (BIN-1));
            }
        }
    }
    if (blockIdx.x == 0 && t < (E & 3)) {
        int j = (E4 << 2) + t;
        int dd = dst[j], ss = src[j];
        int bin = dd >> BSH;
        int pos = atomicAdd(&bcnt[bin], 1);
        if (pos < capb) elist[(size_t)bin * capb + pos] = (ss << BSH) | (dd & (BIN-1));
    }
}

// One block per bin; degree counting via LDS atomics. Exclusive bin ownership:
// eidx slice stores stay in one L2. Epilogue: cursor=deg (write-once),
// dinv = rsqrt(deg+1), y = x*dinv.
__global__ void k_fill3(const int* __restrict__ elist, const int* __restrict__ bcnt,
                        int* __restrict__ cursor, int* __restrict__ eidx,
                        const float* __restrict__ x, float* __restrict__ dinv,
                        float* __restrict__ y, int capb, int CAP, int N) {
    __shared__ int cnt[BIN];
    const int b = blockIdx.x;
    const int bin0 = b << BSH;
    const int tid = threadIdx.x;
    if (tid < BIN) cnt[tid] = 0;
    __syncthreads();
    const int ecnt = min(bcnt[b], capb);
    const int* lst = elist + (size_t)b * capb;
    for (int i0 = tid * 4; i0 + 3 < ecnt; i0 += blockDim.x * 4) {
        iv4 e = *(const iv4*)(lst + i0);
        int l0 = e.x & (BIN-1), s0 = (unsigned)e.x >> BSH;
        int l1 = e.y & (BIN-1), s1 = (unsigned)e.y >> BSH;
        int l2 = e.z & (BIN-1), s2 = (unsigned)e.z >> BSH;
        int l3 = e.w & (BIN-1), s3 = (unsigned)e.w >> BSH;
        int p0 = atomicAdd(&cnt[l0], 1);
        int p1 = atomicAdd(&cnt[l1], 1);
        int p2 = atomicAdd(&cnt[l2], 1);
        int p3 = atomicAdd(&cnt[l3], 1);
        if (p0 < CAP) eidx[(size_t)(bin0 + l0) * CAP + p0] = s0;
        if (p1 < CAP) eidx[(size_t)(bin0 + l1) * CAP + p1] = s1;
        if (p2 < CAP) eidx[(size_t)(bin0 + l2) * CAP + p2] = s2;
        if (p3 < CAP) eidx[(size_t)(bin0 + l3) * CAP + p3] = s3;
    }
    const int tb = ecnt & ~3;
    if (tid < (ecnt & 3)) {
        int e = lst[tb + tid];
        int l = e & (BIN-1);
        int pos = atomicAdd(&cnt[l], 1);
        if (pos < CAP) eidx[(size_t)(bin0 + l) * CAP + pos] = (unsigned)e >> BSH;
    }
    __syncthreads();
    const int node = bin0 + tid;            // threads 0..255 handle the bin's nodes
    if (tid < BIN && node < N) {
        int deg = cnt[tid];
        cursor[node] = deg;                                  // write-once (no pre-zero)
        float di = 1.0f / sqrtf((float)(deg + 1));           // +1 = self-loop
        dinv[node] = di;
        float4 xv = ld4(x + (size_t)node * 4);
        float4 yv; yv.x = xv.x * di; yv.y = xv.y * di; yv.z = xv.z * di; yv.w = xv.w * di;
        *(float4*)(y + (size_t)node * 4) = yv;
    }
}

// Layer 1 + gemm2 fused. Two phases with different thread shapes (R14):
//   phase 1 (latency-bound gather): 4 lanes/node, shfl reduce, raw sum -> LDS.
//   phase 2 (VALU-bound epilogue):  1 thread/node, W1->relu->W2->*dinv ONCE.
// R13's 4-lane epilogue quadrupled VALU; R11's 1-thread gather had 1.5
// waves/SIMD. This gives each phase its right shape.
__global__ void __launch_bounds__(256) k_layer1(
        const int* __restrict__ eidx, const int* __restrict__ degv,
        const float* __restrict__ dinv, const float* __restrict__ y,
        const float* __restrict__ W1, const float* __restrict__ b1,
        const float* __restrict__ W2, float* __restrict__ z, int N, int CAP) {
    __shared__ float sW1[4 * HID];
    __shared__ float sb1[HID];
    __shared__ float sW2[HID * OUTC];
    __shared__ float4 sv_lds[64];
    const int tid = threadIdx.x;
    if (tid < 4 * HID) sW1[tid] = W1[tid];
    if (tid < HID) sb1[tid] = b1[tid];
    for (int i = tid; i < HID * OUTC; i += blockDim.x) sW2[i] = W2[i];
    __syncthreads();

    // --- phase 1: gather, 4 lanes per node ---
    const int g = tid & 3;
    const int nl = tid >> 2;                 // node-local 0..63
    const int n = blockIdx.x * 64 + nl;
    if (n < N) {
        const int deg = min(degv[n], CAP);
        const int* bucket = eidx + (size_t)n * CAP;
        float4 a = {0,0,0,0};
        for (int base = g * 4; base + 3 < deg; base += 16) {
            iv4 q = *(const iv4*)(bucket + base);
            float4 y0 = ld4(y + (size_t)q.x * 4);
            float4 y1 = ld4(y + (size_t)q.y * 4);
            float4 y2 = ld4(y + (size_t)q.z * 4);
            float4 y3 = ld4(y + (size_t)q.w * 4);
            a.x += (y0.x + y1.x) + (y2.x + y3.x);
            a.y += (y0.y + y1.y) + (y2.y + y3.y);
            a.z += (y0.z + y1.z) + (y2.z + y3.z);
            a.w += (y0.w + y1.w) + (y2.w + y3.w);
        }
        const int tb = deg & ~3;
        if (g < (deg & 3)) {
            float4 yv = ld4(y + (size_t)bucket[tb + g] * 4);
            a.x += yv.x; a.y += yv.y; a.z += yv.z; a.w += yv.w;
        }
        a.x += __shfl_xor(a.x, 1); a.y += __shfl_xor(a.y, 1);
        a.z += __shfl_xor(a.z, 1); a.w += __shfl_xor(a.w, 1);
        a.x += __shfl_xor(a.x, 2); a.y += __shfl_xor(a.y, 2);
        a.z += __shfl_xor(a.z, 2); a.w += __shfl_xor(a.w, 2);
        if (g == 0) sv_lds[nl] = a;
    }
    __syncthreads();

    // --- phase 2: epilogue, 1 thread per node (threads 0..63) ---
    if (tid < 64) {
        const int n2 = blockIdx.x * 64 + tid;
        if (n2 < N) {
            const float di = dinv[n2];
            float4 a = sv_lds[tid];
            float4 yn = ld4(y + (size_t)n2 * 4);
            float4 sv;
            sv.x = (a.x + yn.x) * di;
            sv.y = (a.y + yn.y) * di;
            sv.z = (a.z + yn.z) * di;
            sv.w = (a.w + yn.w) * di;
            float r[HID];
#pragma unroll
            for (int c = 0; c < HID; ++c)
                r[c] = fmaxf(sv.x * sW1[c] + sv.y * sW1[HID + c] +
                             sv.z * sW1[2*HID + c] + sv.w * sW1[3*HID + c] + sb1[c], 0.f);
            float o[OUTC] = {};
#pragma unroll
            for (int k = 0; k < HID; ++k) {
                const float rk = r[k];
#pragma unroll
                for (int c = 0; c < OUTC; ++c) o[c] += rk * sW2[k * OUTC + c];
            }
            float* op = z + (size_t)n2 * OUTC;
#pragma unroll
            for (int c = 0; c < OUTC; c += 4) {
                float4 v;
                v.x = o[c]*di; v.y = o[c+1]*di; v.z = o[c+2]*di; v.w = o[c+3]*di;
                *(float4*)(op + c) = v;
            }
        }
    }
}

// Layer 2: 4 lanes/node, 16 z-row-quarter gathers in flight (typical deg=16 ->
// one latency round covers the whole bucket).
__global__ void __launch_bounds__(256) k_agg2(
        const int* __restrict__ eidx, const int* __restrict__ degv,
        const float* __restrict__ dinv, const float* __restrict__ z,
        const float* __restrict__ b2, float* __restrict__ out,
        int N, int CAP) {
    __shared__ float sb[OUTC];
    if (threadIdx.x < OUTC) sb[threadIdx.x] = b2[threadIdx.x];
    __syncthreads();
    const int tid = threadIdx.x;
    const int l4 = (tid & 3) * 4;
    const int n = blockIdx.x * (blockDim.x >> 2) + (tid >> 2);
    if (n >= N) return;
    const int deg = min(degv[n], CAP);
    const int* bucket = eidx + (size_t)n * CAP;
    float4 a0 = {0,0,0,0}, a1 = {0,0,0,0}, a2 = {0,0,0,0}, a3 = {0,0,0,0};
    int i = 0;
    for (; i + 15 < deg; i += 16) {
        iv4 q0 = *(const iv4*)(bucket + i);
        iv4 q1 = *(const iv4*)(bucket + i + 4);
        iv4 q2 = *(const iv4*)(bucket + i + 8);
        iv4 q3 = *(const iv4*)(bucket + i + 12);
        float4 r0 = ld4(z + (size_t)q0.x * OUTC + l4);
        float4 r1 = ld4(z + (size_t)q0.y * OUTC + l4);
        float4 r2 = ld4(z + (size_t)q0.z * OUTC + l4);
        float4 r3 = ld4(z + (size_t)q0.w * OUTC + l4);
        float4 r4 = ld4(z + (size_t)q1.x * OUTC + l4);
        float4 r5 = ld4(z + (size_t)q1.y * OUTC + l4);
        float4 r6 = ld4(z + (size_t)q1.z * OUTC + l4);
        float4 r7 = ld4(z + (size_t)q1.w * OUTC + l4);
        float4 r8 = ld4(z + (size_t)q2.x * OUTC + l4);
        float4 r9 = ld4(z + (size_t)q2.y * OUTC + l4);
        float4 ra = ld4(z + (size_t)q2.z * OUTC + l4);
        float4 rb = ld4(z + (size_t)q2.w * OUTC + l4);
        float4 rc = ld4(z + (size_t)q3.x * OUTC + l4);
        float4 rd = ld4(z + (size_t)q3.y * OUTC + l4);
        float4 re = ld4(z + (size_t)q3.z * OUTC + l4);
        float4 rf = ld4(z + (size_t)q3.w * OUTC + l4);
        a0.x += r0.x + r1.x; a0.y += r0.y + r1.y; a0.z += r0.z + r1.z; a0.w += r0.w + r1.w;
        a1.x += r2.x + r3.x; a1.y += r2.y + r3.y; a1.z += r2.z + r3.z; a1.w += r2.w + r3.w;
        a2.x += r4.x + r5.x; a2.y += r4.y + r5.y; a2.z += r4.z + r5.z; a2.w += r4.w + r5.w;
        a3.x += r6.x + r7.x; a3.y += r6.y + r7.y; a3.z += r6.z + r7.z; a3.w += r6.w + r7.w;
        a0.x += r8.x + r9.x; a0.y += r8.y + r9.y; a0.z += r8.z + r9.z; a0.w += r8.w + r9.w;
        a1.x += ra.x + rb.x; a1.y += ra.y + rb.y; a1.z += ra.z + rb.z; a1.w += ra.w + rb.w;
        a2.x += rc.x + rd.x; a2.y += rc.y + rd.y; a2.z += rc.z + rd.z; a2.w += rc.w + rd.w;
        a3.x += re.x + rf.x; a3.y += re.y + rf.y; a3.z += re.z + rf.z; a3.w += re.w + rf.w;
    }
    for (; i + 3 < deg; i += 4) {
        iv4 q0 = *(const iv4*)(bucket + i);
        float4 r0 = ld4(z + (size_t)q0.x * OUTC + l4);
        float4 r1 = ld4(z + (size_t)q0.y * OUTC + l4);
        float4 r2 = ld4(z + (size_t)q0.z * OUTC + l4);
        float4 r3 = ld4(z + (size_t)q0.w * OUTC + l4);
        a0.x += r0.x + r1.x; a0.y += r0.y + r1.y; a0.z += r0.z + r1.z; a0.w += r0.w + r1.w;
        a1.x += r2.x + r3.x; a1.y += r2.y + r3.y; a1.z += r2.z + r3.z; a1.w += r2.w + r3.w;
    }
    for (; i < deg; ++i) {
        float4 r = ld4(z + (size_t)bucket[i] * OUTC + l4);
        a0.x += r.x; a0.y += r.y; a0.z += r.z; a0.w += r.w;
    }
    const float di = dinv[n];
    float4 zn = ld4(z + (size_t)n * OUTC + l4);
    float4 o;
    o.x = ((a0.x + a1.x) + (a2.x + a3.x) + zn.x) * di + sb[l4 + 0];
    o.y = ((a0.y + a1.y) + (a2.y + a3.y) + zn.y) * di + sb[l4 + 1];
    o.z = ((a0.z + a1.z) + (a2.z + a3.z) + zn.z) * di + sb[l4 + 2];
    o.w = ((a0.w + a1.w) + (a2.w + a3.w) + zn.w) * di + sb[l4 + 3];
    *(float4*)(out + (size_t)n * OUTC + l4) = o;
}

extern "C" void kernel_launch(void* const* d_in, const int* in_sizes, int n_in,
                              void* d_out, int out_size, void* d_ws, size_t ws_size,
                              hipStream_t stream) {
    const float* x  = (const float*)d_in[0];
    const int*   ei = (const int*)d_in[1];
    const float* W1 = (const float*)d_in[2];
    const float* b1 = (const float*)d_in[3];
    const float* W2 = (const float*)d_in[4];
    const float* b2 = (const float*)d_in[5];

    const int N = in_sizes[0] / 4;   // in_c = 4
    const int E = in_sizes[1] / 2;   // edge_index is (2, E)
    const int* src = ei;
    const int* dst = ei + E;

    const int nb = (N + BIN - 1) >> BSH;   // 391 bins at N=100K

    auto align = [](size_t v) { return (v + 255) & ~(size_t)255; };
    int capb = (E / nb + 1024 + 3) & ~3;   // mean E/nb ~4092, sd ~64
    int CAP = 64;                          // Poisson(16): P(deg>64) ~ 1e-13/node
    auto total = [&](int cap, int cb) {
        return align((size_t)N * 4) + align((size_t)MAXNB * 4) + align((size_t)N * 4) +
               align((size_t)N * 4 * 4) + align((size_t)N * OUTC * 4) +
               align((size_t)N * cap * 4) + align((size_t)nb * (size_t)cb * 4);
    };
    while (capb > E / nb + 128 && total(CAP, capb) > ws_size) capb -= 256;
    while (CAP > 40 && total(CAP, capb) > ws_size) CAP -= 8;

    char* ws = (char*)d_ws;
    size_t off = 0;
    int*   cursor = (int*)(ws + off);   off += align((size_t)N * 4);
    int*   bcnt   = (int*)(ws + off);   off += align((size_t)MAXNB * 4);
    float* dinv   = (float*)(ws + off); off += align((size_t)N * 4);
    float* y      = (float*)(ws + off); off += align((size_t)N * 4 * 4);
    float* z      = (float*)(ws + off); off += align((size_t)N * OUTC * 4);
    int*   eidx   = (int*)(ws + off);   off += align((size_t)N * CAP * 4);
    int*   elist  = (int*)(ws + off);   off += align((size_t)nb * (size_t)capb * 4);
    (void)n_in;

    k_zero<<<1, MAXNB, 0, stream>>>(bcnt);
    k_part<<<(E + PTILE - 1) / PTILE, 256, 0, stream>>>(src, dst, bcnt, elist, E, nb, capb);
    k_fill3<<<nb, 512, 0, stream>>>(elist, bcnt, cursor, eidx, x, dinv, y, capb, CAP, N);
    k_layer1<<<(N + 63) / 64, 256, 0, stream>>>(eidx, cursor, dinv, y, W1, b1, W2, z, N, CAP);
    k_agg2<<<(N + 63) / 64, 256, 0, stream>>>(eidx, cursor, dinv, z, b2, (float*)d_out, N, CAP);
    (void)out_size;
}